// Round 4
// baseline (223.898 us; speedup 1.0000x reference)
//
#include <hip/hip_runtime.h>
#include <math.h>

#define D1 768
#define D2R 385
#define NF 295680   // 768*385
#define KNUM 4
#define NB 8
#define NC 256
#define TWOPI_768 0.008181230868723419f
#define INV768 0.0013020833333333333f

// ---------------- ws layout (bytes) --------------------------------------
// specB  bf16 [4][448 c-rows][1536 k]   @ 0          (6,291,456 B)  B^T stage A
// Atw    bf16 [2][768 m][1536 k]        @ 6,291,456  (4,718,592 B)  A stage A
// Ya     bf16 [4][768 m][800 k]         @ 11,010,048 (4,915,200 B)  A stage B
// T      bf16 [768 n][800 k]            @ 15,925,248 (1,228,800 B)  B^T stage B
// SW     f32  [4][768][768]             @ 0          (9,437,184 B)  overlays specB+Atw (dead)
// wBF    bf16 [8][16][9][256][16]       @ 9,437,184  (9,437,184 B)  overlays Ya+T (dead)
#define ATW_U32 1572864u
#define YA_U32 2752512u
#define T_U32 3981312u
#define SPECB_K_U32 344064u  // 448*768 uints per k
#define WBF_BYTE 9437184u

typedef __attribute__((ext_vector_type(8))) short short8;
typedef __attribute__((ext_vector_type(16))) float f32x16;
union U4S8 { unsigned int u[4]; uint4 u4; short8 s8; };

static __device__ __forceinline__ unsigned int f2bf(float f) {
  unsigned int u = __float_as_uint(f);
  return (u + 0x7fffu + ((u >> 16) & 1u)) >> 16;  // RNE, no NaN inputs
}

// hw sin/cos: v_sin_f32/v_cos_f32 take REVOLUTIONS; idx in [0,768) -> idx/768
static __device__ __forceinline__ void sincos_rev768(int idx, float* s,
                                                     float* c) {
  float rev = (float)idx * INV768;
  *s = __builtin_amdgcn_sinf(rev);
  *c = __builtin_amdgcn_cosf(rev);
}

// raw barrier: LDS-drain only; register-dest vmem loads stay in flight.
static __device__ __forceinline__ void barrier_lgkm() {
  asm volatile("s_waitcnt lgkmcnt(0)" ::: "memory");
  __builtin_amdgcn_sched_barrier(0);
  __builtin_amdgcn_s_barrier();
  __builtin_amdgcn_sched_barrier(0);
}

// ---------------- prep: scatter + twiddle matrices + zero pads -----------
__global__ __launch_bounds__(256) void prep_kernel(
    const float* __restrict__ dw, const int* __restrict__ fh,
    const int* __restrict__ fw, unsigned int* __restrict__ ws) {
  long i = (long)blockIdx.x * 256 + threadIdx.x;  // grid 11364
  if (i < 1182720) {  // scatter: dft_weight -> bf16 B^T spectrum
    int k = (int)(i / NF);
    int r = (int)(i - (long)k * NF);
    const float2 v = ((const float2*)dw)[i];
    int h = fh[r], c = fw[r];
    ws[(size_t)k * SPECB_K_U32 + (size_t)c * 768 + h] =
        f2bf(v.x) | (f2bf(v.y) << 16);
    return;
  }
  long j = i - 1182720;
  if (j < 1179648) {  // Atw: A_re/A_im [768 m][1536 k=2h]
    int ri = (int)(j / 589824);
    int rem = (int)(j - (long)ri * 589824);
    int m = rem / 768, h = rem - (rem / 768) * 768;
    int idx = (h * m) % 768;
    float s, c;
    sincos_rev768(idx, &s, &c);
    unsigned lo, hi;
    if (ri == 0) { lo = f2bf(c); hi = f2bf(-s); }
    else         { lo = f2bf(s); hi = f2bf(c); }
    ws[ATW_U32 + j] = lo | (hi << 16);
  } else if (j < 1486848) {  // T^T [768 n][800 k=2c]
    long p = j - 1179648;
    int n = (int)(p / 400), cc = (int)(p - (p / 400) * 400);
    unsigned v = 0;
    if (cc <= 384) {
      float wgt = (cc == 0 || cc == 384) ? 1.6954210069444445e-6f
                                         : 3.390842013888889e-6f;
      int idx = (cc * n) % 768;
      float s, c;
      sincos_rev768(idx, &s, &c);
      v = f2bf(wgt * c) | (f2bf(-wgt * s) << 16);
    }
    ws[T_U32 + (size_t)n * 400 + cc] = v;
  } else if (j < 1680384) {  // specB zero rows 385..447
    long p = j - 1486848;
    int k = (int)(p / 48384);
    long r = p - (long)k * 48384;
    int row = 385 + (int)(r / 768);
    int col = (int)(r - (r / 768) * 768);
    ws[(size_t)k * SPECB_K_U32 + (size_t)row * 768 + col] = 0u;
  } else if (j < 1726464) {  // Ya zero cols 770..799
    long p = j - 1680384;
    int k = (int)(p / 11520);
    long r = p - (long)k * 11520;
    int m = (int)(r / 15), jj = (int)(r - (r / 15) * 15);
    ws[YA_U32 + (size_t)k * 307200 + (size_t)m * 400 + 385 + jj] = 0u;
  }
}

// ---------------- fftA v2: 128m x 64n block, wave 64x32 (acc[2]) ---------
// LDS-op cut: A-frag reused across 2 m-subs -> 6 reads per 4 MFMA (was 2:1).
// grid (6,7,8); all blocks co-resident (LDS 30.7KB -> 2/CU).
__global__ __launch_bounds__(256) void fftA_kernel(
    const unsigned short* __restrict__ Atw,
    const unsigned short* __restrict__ specB,
    unsigned short* __restrict__ Ya) {
  __shared__ __align__(16) unsigned short Al[2][128 * 40], Bl[2][64 * 40];
  int t = threadIdx.x;
  int mt = blockIdx.x, nt = blockIdx.y, z = blockIdx.z;
  int ri = z & 1, k = z >> 1;
  const unsigned short* Ag =
      Atw + (size_t)ri * 1179648 + (size_t)(mt * 128) * 1536;
  const unsigned short* Bg =
      specB + (size_t)k * 688128 + (size_t)(nt * 64) * 1536;
  int rowA = t >> 1, qa = t & 1;  // A: 128 rows x 2 chunks of 16 shorts
  int rowB = t >> 2, qb = t & 3;  // B: 64 rows x 4 chunks of 8 shorts
  int lane = t & 63, w = t >> 6;
  int mq = w & 1, nq = w >> 1;
  int lm = lane & 31, half = lane >> 5;
  int wrA = rowA * 40 + qa * 16;
  int wrB = rowB * 40 + qb * 8;
  int ao0 = (mq * 64 + lm) * 40 + half * 8;
  int ao1 = (mq * 64 + 32 + lm) * 40 + half * 8;
  int bo = (nq * 32 + lm) * 40 + half * 8;

  f32x16 acc[2];
#pragma unroll
  for (int i = 0; i < 2; ++i)
#pragma unroll
    for (int r = 0; r < 16; ++r) acc[i][r] = 0.f;

  uint4 av0 = *(const uint4*)(Ag + (size_t)rowA * 1536 + qa * 16);
  uint4 av1 = *(const uint4*)(Ag + (size_t)rowA * 1536 + qa * 16 + 8);
  uint4 bv = *(const uint4*)(Bg + (size_t)rowB * 1536 + qb * 8);
  *(uint4*)&Al[0][wrA] = av0;
  *(uint4*)&Al[0][wrA + 8] = av1;
  *(uint4*)&Bl[0][wrB] = bv;
  __syncthreads();

  for (int kb = 0; kb < 48; ++kb) {
    bool more = (kb < 47);
    if (more) {
      av0 = *(const uint4*)(Ag + (size_t)rowA * 1536 + (kb + 1) * 32 + qa * 16);
      av1 = *(const uint4*)(Ag + (size_t)rowA * 1536 + (kb + 1) * 32 + qa * 16 + 8);
      bv = *(const uint4*)(Bg + (size_t)rowB * 1536 + (kb + 1) * 32 + qb * 8);
    }
    const unsigned short* Ab = Al[kb & 1];
    const unsigned short* Bb = Bl[kb & 1];
#pragma unroll
    for (int kk2 = 0; kk2 < 2; ++kk2) {
      short8 b8 = *(const short8*)&Bb[bo + kk2 * 16];
      short8 a80 = *(const short8*)&Ab[ao0 + kk2 * 16];
      short8 a81 = *(const short8*)&Ab[ao1 + kk2 * 16];
      acc[0] = __builtin_amdgcn_mfma_f32_32x32x16_bf16(a80, b8, acc[0], 0, 0, 0);
      acc[1] = __builtin_amdgcn_mfma_f32_32x32x16_bf16(a81, b8, acc[1], 0, 0, 0);
    }
    if (more) {
      *(uint4*)&Al[(kb + 1) & 1][wrA] = av0;
      *(uint4*)&Al[(kb + 1) & 1][wrA + 8] = av1;
      *(uint4*)&Bl[(kb + 1) & 1][wrB] = bv;
    }
    __syncthreads();
  }

  int c = nt * 64 + nq * 32 + lm;
  if (c < D2R) {
    unsigned short* Yk = Ya + (size_t)k * 614400;
#pragma unroll
    for (int i = 0; i < 2; ++i) {
      int mb = mt * 128 + mq * 64 + i * 32 + 4 * half;
#pragma unroll
      for (int reg = 0; reg < 16; ++reg) {
        int m = mb + (reg & 3) + 8 * (reg >> 2);
        Yk[(size_t)m * 800 + 2 * c + ri] = (unsigned short)f2bf(acc[i][reg]);
      }
    }
  }
}

// ---------------- fftB v2: 128m x 64n block, wave 64x32 (acc[2]) ---------
__global__ __launch_bounds__(256) void fftB_kernel(
    const unsigned short* __restrict__ Ya, const unsigned short* __restrict__ T,
    float* __restrict__ SW) {
  __shared__ __align__(16) unsigned short Al[2][128 * 40], Bl[2][64 * 40];
  int t = threadIdx.x;
  int mt = blockIdx.x, nt = blockIdx.y, k = blockIdx.z;
  const unsigned short* Ag = Ya + (size_t)k * 614400 + (size_t)(mt * 128) * 800;
  const unsigned short* Bg = T + (size_t)(nt * 64) * 800;
  int rowA = t >> 1, qa = t & 1;
  int rowB = t >> 2, qb = t & 3;
  int lane = t & 63, w = t >> 6;
  int mq = w & 1, nq = w >> 1;
  int lm = lane & 31, half = lane >> 5;
  int wrA = rowA * 40 + qa * 16;
  int wrB = rowB * 40 + qb * 8;
  int ao0 = (mq * 64 + lm) * 40 + half * 8;
  int ao1 = (mq * 64 + 32 + lm) * 40 + half * 8;
  int bo = (nq * 32 + lm) * 40 + half * 8;

  f32x16 acc[2];
#pragma unroll
  for (int i = 0; i < 2; ++i)
#pragma unroll
    for (int r = 0; r < 16; ++r) acc[i][r] = 0.f;

  uint4 av0 = *(const uint4*)(Ag + (size_t)rowA * 800 + qa * 16);
  uint4 av1 = *(const uint4*)(Ag + (size_t)rowA * 800 + qa * 16 + 8);
  uint4 bv = *(const uint4*)(Bg + (size_t)rowB * 800 + qb * 8);
  *(uint4*)&Al[0][wrA] = av0;
  *(uint4*)&Al[0][wrA + 8] = av1;
  *(uint4*)&Bl[0][wrB] = bv;
  __syncthreads();

  for (int kb = 0; kb < 25; ++kb) {
    bool more = (kb < 24);
    if (more) {
      av0 = *(const uint4*)(Ag + (size_t)rowA * 800 + (kb + 1) * 32 + qa * 16);
      av1 = *(const uint4*)(Ag + (size_t)rowA * 800 + (kb + 1) * 32 + qa * 16 + 8);
      bv = *(const uint4*)(Bg + (size_t)rowB * 800 + (kb + 1) * 32 + qb * 8);
    }
    const unsigned short* Ab = Al[kb & 1];
    const unsigned short* Bb = Bl[kb & 1];
#pragma unroll
    for (int kk2 = 0; kk2 < 2; ++kk2) {
      short8 b8 = *(const short8*)&Bb[bo + kk2 * 16];
      short8 a80 = *(const short8*)&Ab[ao0 + kk2 * 16];
      short8 a81 = *(const short8*)&Ab[ao1 + kk2 * 16];
      acc[0] = __builtin_amdgcn_mfma_f32_32x32x16_bf16(a80, b8, acc[0], 0, 0, 0);
      acc[1] = __builtin_amdgcn_mfma_f32_32x32x16_bf16(a81, b8, acc[1], 0, 0, 0);
    }
    if (more) {
      *(uint4*)&Al[(kb + 1) & 1][wrA] = av0;
      *(uint4*)&Al[(kb + 1) & 1][wrA + 8] = av1;
      *(uint4*)&Bl[(kb + 1) & 1][wrB] = bv;
    }
    __syncthreads();
  }

  float* SWk = SW + (size_t)k * 589824;
  int n = nt * 64 + nq * 32 + lm;
#pragma unroll
  for (int i = 0; i < 2; ++i) {
    int mb = mt * 128 + mq * 64 + i * 32 + 4 * half;
#pragma unroll
    for (int reg = 0; reg < 16; ++reg) {
      int m = mb + (reg & 3) + 8 * (reg >> 2);
      SWk[(size_t)m * 768 + n] = acc[i][reg];
    }
  }
}

// ---------------- wprep v2: 1 block per SW row, LDS-staged coalesced -----
__global__ __launch_bounds__(256) void wprep_kernel(
    const float* __restrict__ ka, const float* __restrict__ SW,
    unsigned short* __restrict__ wBF) {
  __shared__ float rowL[4][768];
  int t = threadIdx.x;
  int row = blockIdx.x;  // grid 768: row = oc*3 + dy
  int oc = row / 3, dy = row - oc * 3;
  if (t < 192) {
#pragma unroll
    for (int k = 0; k < 4; ++k)
      *(float4*)&rowL[k][t * 4] =
          *(const float4*)(SW + (size_t)k * 589824 + (size_t)row * 768 + t * 4);
  }
  float att[8][4];
#pragma unroll
  for (int b = 0; b < 8; ++b)
#pragma unroll
    for (int k = 0; k < 4; ++k)
      att[b][k] = 0.5f / (1.f + expf(-ka[b * 4 + k]));
  __syncthreads();
  int icb = t >> 4, i = t & 15;
#pragma unroll
  for (int dx = 0; dx < 3; ++dx) {
    int col = icb * 48 + dx + 3 * i;
    float v0 = rowL[0][col], v1 = rowL[1][col], v2 = rowL[2][col],
          v3 = rowL[3][col];
    int s = dy * 3 + dx;
#pragma unroll
    for (int b = 0; b < 8; ++b) {
      float v = att[b][0] * v0 + att[b][1] * v1 + att[b][2] * v2 +
                att[b][3] * v3;
      wBF[(((size_t)(b * 16 + icb) * 9 + s) * 256 + oc) * 16 + i] =
          (unsigned short)f2bf(v);
    }
  }
}

// ---------------- conv v8: conflict-free staging + XCD-L2 swizzle --------
// r3 post-mortem: (a) stage_write 8-way bank conflict (3.67M counted):
// px stride 48B == 16 words -> 4 start-banks. Fix: site stride 40B (10
// words, ==2 mod 4) + each write-instr spans px at stride-1 sites (thread
// owns px {p,p+16,p+32,p+48}) -> banks 20*sub+10*px4 = uniform 4/bank
// (b64 floor). Loads become 16 coalesced dwords (same line count).
// (b) wBF refill = 590MB L2/L3 traffic; slices scattered over XCDs ->
// L3-BW bound (~12 TB/s observed r1/r3). Fix: 1D grid, xcd=orig&7 owns
// slices {2x,2x+1} (= batch b=x, both octs): per-XCD wBF 1.15MB -> L2.
__global__ __launch_bounds__(256, 2) void conv_mfma_kernel(
    const float* __restrict__ x, const unsigned short* __restrict__ wBF,
    float* __restrict__ out) {
  __shared__ __align__(16) unsigned char ldsX[2][4 * 66 * 40];
  int t = threadIdx.x;
  // XCD swizzle: hw round-robins consecutive blockIdx across 8 XCDs.
  int orig = blockIdx.x;  // grid 512
  int xcd = orig & 7, seq = orig >> 3;
  int slice = xcd * 2 + (seq >> 5);  // = b*2 + oct; XCD x owns b = x
  int pxt = seq & 31;
  int b = slice >> 1, oct = slice & 1;
  int py0 = pxt * 2, oc0 = oct * 128;
  int lane = t & 63, w = t >> 6;
  int ocq = w >> 1, pxq = w & 1;
  int n = lane & 31, half = lane >> 5;

  // zero halo cols (c=0,65; rows 0..3) in both buffers, once (10 words/site)
  if (t < 160) {
    int buf = t / 80, r2 = t - buf * 80;
    int site = r2 / 10, word = r2 - site * 10;
    int r = site >> 1, c = (site & 1) ? 65 : 0;
    *(unsigned int*)(&ldsX[buf][(r * 66 + c) * 40 + word * 4]) = 0u;
  }

  f32x16 acc[2][2];
#pragma unroll
  for (int i = 0; i < 2; ++i)
#pragma unroll
    for (int j = 0; j < 2; ++j)
#pragma unroll
      for (int r = 0; r < 16; ++r) acc[i][j][r] = 0.f;

  // staging role: thread owns ic w*4..w*4+3, row sub, px {px4,+16,+32,+48}
  int px4 = lane & 15, sub = lane >> 4;
  int iy = py0 - 1 + sub;
  bool valid = (iy >= 0 && iy < 64);
  const float* xpb =
      x + (((size_t)(b * NC + w * 4)) * 64 + (valid ? iy : 0)) * 64 + px4;
  unsigned char* xw0 = (unsigned char*)&ldsX[0][0] + (sub * 66 + 1 + px4) * 40 + w * 8;
  unsigned char* xw1 = (unsigned char*)&ldsX[1][0] + (sub * 66 + 1 + px4) * 40 + w * 8;

  float a[4][4];  // [ic j][pp]
#pragma unroll
  for (int j = 0; j < 4; ++j)
#pragma unroll
    for (int pp = 0; pp < 4; ++pp) a[j][pp] = 0.f;
  if (valid) {
#pragma unroll
    for (int j = 0; j < 4; ++j) {
      const float* pj = xpb + (size_t)j * 4096;
#pragma unroll
      for (int pp = 0; pp < 4; ++pp) a[j][pp] = pj[pp * 16];
    }
  }

  // A-frag ring (depth 9 = one full icb lookahead), layout [b][step][oc][16]
  const uint4* wg4 = (const uint4*)wBF;
  size_t abase =
      (size_t)b * 144 * 512 + (size_t)(oc0 + ocq * 64 + n) * 2 + half;
  U4S8 pf[9][2];
#pragma unroll
  for (int i = 0; i < 9; ++i) {
    pf[i][0].u4 = wg4[abase + (size_t)i * 512];
    pf[i][1].u4 = wg4[abase + (size_t)i * 512 + 64];
  }

  // prologue: stage icb 0 into buf 0 (write-instr pp spans px stride 16)
#pragma unroll
  for (int pp = 0; pp < 4; ++pp) {
    uint2 wv;
    wv.x = f2bf(a[0][pp]) | (f2bf(a[1][pp]) << 16);
    wv.y = f2bf(a[2][pp]) | (f2bf(a[3][pp]) << 16);
    *(uint2*)(xw0 + pp * 640) = wv;  // 16 sites * 40B
  }
  barrier_lgkm();

  for (int icb = 0; icb < 16; ++icb) {
    // issue next x-tile loads (16 coalesced dwords)
#pragma unroll
    for (int j = 0; j < 4; ++j)
#pragma unroll
      for (int pp = 0; pp < 4; ++pp) a[j][pp] = 0.f;
    if (icb < 15 && valid) {
      const float* p0 = xpb + (size_t)(icb + 1) * 16 * 4096;
#pragma unroll
      for (int j = 0; j < 4; ++j) {
        const float* pj = p0 + (size_t)j * 4096;
#pragma unroll
        for (int pp = 0; pp < 4; ++pp) a[j][pp] = pj[pp * 16];
      }
    }
    const unsigned char* bufR = &ldsX[icb & 1][0];
#pragma unroll
    for (int s = 0; s < 9; ++s) {
      int step = icb * 9 + s;
      int dy = s / 3, dx = s - dy * 3;
      const unsigned char* bb =
          bufR + ((pxq + dy) * 66 + n + dx) * 40 + half * 16;
      short8 B0 = *(const short8*)bb;
      short8 B1 = *(const short8*)(bb + 32 * 40);
      acc[0][0] = __builtin_amdgcn_mfma_f32_32x32x16_bf16(pf[s][0].s8, B0,
                                                          acc[0][0], 0, 0, 0);
      acc[0][1] = __builtin_amdgcn_mfma_f32_32x32x16_bf16(pf[s][0].s8, B1,
                                                          acc[0][1], 0, 0, 0);
      acc[1][0] = __builtin_amdgcn_mfma_f32_32x32x16_bf16(pf[s][1].s8, B0,
                                                          acc[1][0], 0, 0, 0);
      acc[1][1] = __builtin_amdgcn_mfma_f32_32x32x16_bf16(pf[s][1].s8, B1,
                                                          acc[1][1], 0, 0, 0);
      if (icb < 15) {  // refill ring slot s for next icb (WAR after mfma)
        pf[s][0].u4 = wg4[abase + (size_t)(step + 9) * 512];
        pf[s][1].u4 = wg4[abase + (size_t)(step + 9) * 512 + 64];
      }
    }
    if (icb < 15) {  // convert + write next tile into other buffer
      unsigned char* xw = (icb & 1) ? xw0 : xw1;
#pragma unroll
      for (int pp = 0; pp < 4; ++pp) {
        uint2 wv;
        wv.x = f2bf(a[0][pp]) | (f2bf(a[1][pp]) << 16);
        wv.y = f2bf(a[2][pp]) | (f2bf(a[3][pp]) << 16);
        *(uint2*)(xw + pp * 640) = wv;
      }
    }
    barrier_lgkm();
  }

  int py = py0 + pxq;
#pragma unroll
  for (int osub = 0; osub < 2; ++osub)
#pragma unroll
    for (int psub = 0; psub < 2; ++psub) {
      int OC = oc0 + ocq * 64 + osub * 32 + 4 * half;
      int pxc = psub * 32 + n;
      float* op = out + (((size_t)(b * NC + OC)) * 64 + py) * 64 + pxc;
#pragma unroll
      for (int reg = 0; reg < 16; ++reg) {
        int ocm = (reg & 3) + 8 * (reg >> 2);
        op[(size_t)ocm * 4096] = acc[osub][psub][reg];
      }
    }
}

extern "C" void kernel_launch(void* const* d_in, const int* in_sizes, int n_in,
                              void* d_out, int out_size, void* d_ws,
                              size_t ws_size, hipStream_t stream) {
  const float* x = (const float*)d_in[0];
  const float* dw = (const float*)d_in[1];
  const float* ka = (const float*)d_in[2];
  const int* fh = (const int*)d_in[3];
  const int* fw = (const int*)d_in[4];
  float* out = (float*)d_out;
  unsigned int* ws = (unsigned int*)d_ws;
  const unsigned short* specB = (const unsigned short*)d_ws;
  const unsigned short* Atw = (const unsigned short*)((char*)d_ws + 6291456);
  unsigned short* Ya = (unsigned short*)((char*)d_ws + 11010048);
  const unsigned short* T = (const unsigned short*)((char*)d_ws + 15925248);
  float* SW = (float*)d_ws;
  unsigned short* wBF = (unsigned short*)((char*)d_ws + WBF_BYTE);

  hipLaunchKernelGGL(prep_kernel, dim3(11364), dim3(256), 0, stream, dw, fh,
                     fw, ws);
  hipLaunchKernelGGL(fftA_kernel, dim3(6, 7, 8), dim3(256), 0, stream, Atw,
                     specB, Ya);
  hipLaunchKernelGGL(fftB_kernel, dim3(6, 12, KNUM), dim3(256), 0, stream, Ya,
                     T, SW);
  hipLaunchKernelGGL(wprep_kernel, dim3(768), dim3(256), 0, stream, ka, SW,
                     wBF);
  hipLaunchKernelGGL(conv_mfma_kernel, dim3(512), dim3(256), 0, stream, x,
                     wBF, out);
}

// Round 5
// 194.616 us; speedup vs baseline: 1.1505x; 1.1505x over previous
//
#include <hip/hip_runtime.h>
#include <math.h>

#define D1 768
#define D2R 385
#define NF 295680   // 768*385
#define KNUM 4
#define NB 8
#define NC 256
#define TWOPI_768 0.008181230868723419f
#define INV768 0.0013020833333333333f

// ---------------- ws layout (bytes) --------------------------------------
// specB  bf16 [4][448 c-rows][1536 k]   @ 0          (6,291,456 B)  B^T stage A
// Atw    bf16 [2][768 m][1536 k]        @ 6,291,456  (4,718,592 B)  A stage A
// Ya     bf16 [4][768 m][800 k]         @ 11,010,048 (4,915,200 B)  A stage B
// T      bf16 [768 n][800 k]            @ 15,925,248 (1,228,800 B)  B^T stage B
// SW     f32  [4][768][768]             @ 0          (9,437,184 B)  overlays specB+Atw (dead)
// wBF    bf16 [8][16][9][256][16]       @ 9,437,184  (9,437,184 B)  overlays Ya+T (dead)
#define ATW_U32 1572864u
#define YA_U32 2752512u
#define T_U32 3981312u
#define SPECB_K_U32 344064u  // 448*768 uints per k
#define WBF_BYTE 9437184u

typedef __attribute__((ext_vector_type(8))) short short8;
typedef __attribute__((ext_vector_type(16))) float f32x16;
union U4S8 { unsigned int u[4]; uint4 u4; short8 s8; };

static __device__ __forceinline__ unsigned int f2bf(float f) {
  unsigned int u = __float_as_uint(f);
  return (u + 0x7fffu + ((u >> 16) & 1u)) >> 16;  // RNE, no NaN inputs
}

// hw sin/cos: v_sin_f32/v_cos_f32 take REVOLUTIONS; idx in [0,768) -> idx/768
static __device__ __forceinline__ void sincos_rev768(int idx, float* s,
                                                     float* c) {
  float rev = (float)idx * INV768;
  *s = __builtin_amdgcn_sinf(rev);
  *c = __builtin_amdgcn_cosf(rev);
}

// raw barrier: LDS-drain only; register-dest vmem loads stay in flight.
static __device__ __forceinline__ void barrier_lgkm() {
  asm volatile("s_waitcnt lgkmcnt(0)" ::: "memory");
  __builtin_amdgcn_sched_barrier(0);
  __builtin_amdgcn_s_barrier();
  __builtin_amdgcn_sched_barrier(0);
}

// ---------------- prep: scatter + twiddle matrices + zero pads -----------
__global__ __launch_bounds__(256) void prep_kernel(
    const float* __restrict__ dw, const int* __restrict__ fh,
    const int* __restrict__ fw, unsigned int* __restrict__ ws) {
  long i = (long)blockIdx.x * 256 + threadIdx.x;  // grid 11364
  if (i < 1182720) {  // scatter: dft_weight -> bf16 B^T spectrum
    int k = (int)(i / NF);
    int r = (int)(i - (long)k * NF);
    const float2 v = ((const float2*)dw)[i];
    int h = fh[r], c = fw[r];
    ws[(size_t)k * SPECB_K_U32 + (size_t)c * 768 + h] =
        f2bf(v.x) | (f2bf(v.y) << 16);
    return;
  }
  long j = i - 1182720;
  if (j < 1179648) {  // Atw: A_re/A_im [768 m][1536 k=2h]
    int ri = (int)(j / 589824);
    int rem = (int)(j - (long)ri * 589824);
    int m = rem / 768, h = rem - (rem / 768) * 768;
    int idx = (h * m) % 768;
    float s, c;
    sincos_rev768(idx, &s, &c);
    unsigned lo, hi;
    if (ri == 0) { lo = f2bf(c); hi = f2bf(-s); }
    else         { lo = f2bf(s); hi = f2bf(c); }
    ws[ATW_U32 + j] = lo | (hi << 16);
  } else if (j < 1486848) {  // T^T [768 n][800 k=2c]
    long p = j - 1179648;
    int n = (int)(p / 400), cc = (int)(p - (p / 400) * 400);
    unsigned v = 0;
    if (cc <= 384) {
      float wgt = (cc == 0 || cc == 384) ? 1.6954210069444445e-6f
                                         : 3.390842013888889e-6f;
      int idx = (cc * n) % 768;
      float s, c;
      sincos_rev768(idx, &s, &c);
      v = f2bf(wgt * c) | (f2bf(-wgt * s) << 16);
    }
    ws[T_U32 + (size_t)n * 400 + cc] = v;
  } else if (j < 1680384) {  // specB zero rows 385..447
    long p = j - 1486848;
    int k = (int)(p / 48384);
    long r = p - (long)k * 48384;
    int row = 385 + (int)(r / 768);
    int col = (int)(r - (r / 768) * 768);
    ws[(size_t)k * SPECB_K_U32 + (size_t)row * 768 + col] = 0u;
  } else if (j < 1726464) {  // Ya zero cols 770..799
    long p = j - 1680384;
    int k = (int)(p / 11520);
    long r = p - (long)k * 11520;
    int m = (int)(r / 15), jj = (int)(r - (r / 15) * 15);
    ws[YA_U32 + (size_t)k * 307200 + (size_t)m * 400 + 385 + jj] = 0u;
  }
}

// ---------------- fftA v2: 128m x 64n block, wave 64x32 (acc[2]) ---------
__global__ __launch_bounds__(256) void fftA_kernel(
    const unsigned short* __restrict__ Atw,
    const unsigned short* __restrict__ specB,
    unsigned short* __restrict__ Ya) {
  __shared__ __align__(16) unsigned short Al[2][128 * 40], Bl[2][64 * 40];
  int t = threadIdx.x;
  int mt = blockIdx.x, nt = blockIdx.y, z = blockIdx.z;
  int ri = z & 1, k = z >> 1;
  const unsigned short* Ag =
      Atw + (size_t)ri * 1179648 + (size_t)(mt * 128) * 1536;
  const unsigned short* Bg =
      specB + (size_t)k * 688128 + (size_t)(nt * 64) * 1536;
  int rowA = t >> 1, qa = t & 1;  // A: 128 rows x 2 chunks of 16 shorts
  int rowB = t >> 2, qb = t & 3;  // B: 64 rows x 4 chunks of 8 shorts
  int lane = t & 63, w = t >> 6;
  int mq = w & 1, nq = w >> 1;
  int lm = lane & 31, half = lane >> 5;
  int wrA = rowA * 40 + qa * 16;
  int wrB = rowB * 40 + qb * 8;
  int ao0 = (mq * 64 + lm) * 40 + half * 8;
  int ao1 = (mq * 64 + 32 + lm) * 40 + half * 8;
  int bo = (nq * 32 + lm) * 40 + half * 8;

  f32x16 acc[2];
#pragma unroll
  for (int i = 0; i < 2; ++i)
#pragma unroll
    for (int r = 0; r < 16; ++r) acc[i][r] = 0.f;

  uint4 av0 = *(const uint4*)(Ag + (size_t)rowA * 1536 + qa * 16);
  uint4 av1 = *(const uint4*)(Ag + (size_t)rowA * 1536 + qa * 16 + 8);
  uint4 bv = *(const uint4*)(Bg + (size_t)rowB * 1536 + qb * 8);
  *(uint4*)&Al[0][wrA] = av0;
  *(uint4*)&Al[0][wrA + 8] = av1;
  *(uint4*)&Bl[0][wrB] = bv;
  __syncthreads();

  for (int kb = 0; kb < 48; ++kb) {
    bool more = (kb < 47);
    if (more) {
      av0 = *(const uint4*)(Ag + (size_t)rowA * 1536 + (kb + 1) * 32 + qa * 16);
      av1 = *(const uint4*)(Ag + (size_t)rowA * 1536 + (kb + 1) * 32 + qa * 16 + 8);
      bv = *(const uint4*)(Bg + (size_t)rowB * 1536 + (kb + 1) * 32 + qb * 8);
    }
    const unsigned short* Ab = Al[kb & 1];
    const unsigned short* Bb = Bl[kb & 1];
#pragma unroll
    for (int kk2 = 0; kk2 < 2; ++kk2) {
      short8 b8 = *(const short8*)&Bb[bo + kk2 * 16];
      short8 a80 = *(const short8*)&Ab[ao0 + kk2 * 16];
      short8 a81 = *(const short8*)&Ab[ao1 + kk2 * 16];
      acc[0] = __builtin_amdgcn_mfma_f32_32x32x16_bf16(a80, b8, acc[0], 0, 0, 0);
      acc[1] = __builtin_amdgcn_mfma_f32_32x32x16_bf16(a81, b8, acc[1], 0, 0, 0);
    }
    if (more) {
      *(uint4*)&Al[(kb + 1) & 1][wrA] = av0;
      *(uint4*)&Al[(kb + 1) & 1][wrA + 8] = av1;
      *(uint4*)&Bl[(kb + 1) & 1][wrB] = bv;
    }
    __syncthreads();
  }

  int c = nt * 64 + nq * 32 + lm;
  if (c < D2R) {
    unsigned short* Yk = Ya + (size_t)k * 614400;
#pragma unroll
    for (int i = 0; i < 2; ++i) {
      int mb = mt * 128 + mq * 64 + i * 32 + 4 * half;
#pragma unroll
      for (int reg = 0; reg < 16; ++reg) {
        int m = mb + (reg & 3) + 8 * (reg >> 2);
        Yk[(size_t)m * 800 + 2 * c + ri] = (unsigned short)f2bf(acc[i][reg]);
      }
    }
  }
}

// ---------------- fftB v2: 128m x 64n block, wave 64x32 (acc[2]) ---------
__global__ __launch_bounds__(256) void fftB_kernel(
    const unsigned short* __restrict__ Ya, const unsigned short* __restrict__ T,
    float* __restrict__ SW) {
  __shared__ __align__(16) unsigned short Al[2][128 * 40], Bl[2][64 * 40];
  int t = threadIdx.x;
  int mt = blockIdx.x, nt = blockIdx.y, k = blockIdx.z;
  const unsigned short* Ag = Ya + (size_t)k * 614400 + (size_t)(mt * 128) * 800;
  const unsigned short* Bg = T + (size_t)(nt * 64) * 800;
  int rowA = t >> 1, qa = t & 1;
  int rowB = t >> 2, qb = t & 3;
  int lane = t & 63, w = t >> 6;
  int mq = w & 1, nq = w >> 1;
  int lm = lane & 31, half = lane >> 5;
  int wrA = rowA * 40 + qa * 16;
  int wrB = rowB * 40 + qb * 8;
  int ao0 = (mq * 64 + lm) * 40 + half * 8;
  int ao1 = (mq * 64 + 32 + lm) * 40 + half * 8;
  int bo = (nq * 32 + lm) * 40 + half * 8;

  f32x16 acc[2];
#pragma unroll
  for (int i = 0; i < 2; ++i)
#pragma unroll
    for (int r = 0; r < 16; ++r) acc[i][r] = 0.f;

  uint4 av0 = *(const uint4*)(Ag + (size_t)rowA * 800 + qa * 16);
  uint4 av1 = *(const uint4*)(Ag + (size_t)rowA * 800 + qa * 16 + 8);
  uint4 bv = *(const uint4*)(Bg + (size_t)rowB * 800 + qb * 8);
  *(uint4*)&Al[0][wrA] = av0;
  *(uint4*)&Al[0][wrA + 8] = av1;
  *(uint4*)&Bl[0][wrB] = bv;
  __syncthreads();

  for (int kb = 0; kb < 25; ++kb) {
    bool more = (kb < 24);
    if (more) {
      av0 = *(const uint4*)(Ag + (size_t)rowA * 800 + (kb + 1) * 32 + qa * 16);
      av1 = *(const uint4*)(Ag + (size_t)rowA * 800 + (kb + 1) * 32 + qa * 16 + 8);
      bv = *(const uint4*)(Bg + (size_t)rowB * 800 + (kb + 1) * 32 + qb * 8);
    }
    const unsigned short* Ab = Al[kb & 1];
    const unsigned short* Bb = Bl[kb & 1];
#pragma unroll
    for (int kk2 = 0; kk2 < 2; ++kk2) {
      short8 b8 = *(const short8*)&Bb[bo + kk2 * 16];
      short8 a80 = *(const short8*)&Ab[ao0 + kk2 * 16];
      short8 a81 = *(const short8*)&Ab[ao1 + kk2 * 16];
      acc[0] = __builtin_amdgcn_mfma_f32_32x32x16_bf16(a80, b8, acc[0], 0, 0, 0);
      acc[1] = __builtin_amdgcn_mfma_f32_32x32x16_bf16(a81, b8, acc[1], 0, 0, 0);
    }
    if (more) {
      *(uint4*)&Al[(kb + 1) & 1][wrA] = av0;
      *(uint4*)&Al[(kb + 1) & 1][wrA + 8] = av1;
      *(uint4*)&Bl[(kb + 1) & 1][wrB] = bv;
    }
    __syncthreads();
  }

  float* SWk = SW + (size_t)k * 589824;
  int n = nt * 64 + nq * 32 + lm;
#pragma unroll
  for (int i = 0; i < 2; ++i) {
    int mb = mt * 128 + mq * 64 + i * 32 + 4 * half;
#pragma unroll
    for (int reg = 0; reg < 16; ++reg) {
      int m = mb + (reg & 3) + 8 * (reg >> 2);
      SWk[(size_t)m * 768 + n] = acc[i][reg];
    }
  }
}

// ---------------- wprep v2: 1 block per SW row, LDS-staged coalesced -----
__global__ __launch_bounds__(256) void wprep_kernel(
    const float* __restrict__ ka, const float* __restrict__ SW,
    unsigned short* __restrict__ wBF) {
  __shared__ float rowL[4][768];
  int t = threadIdx.x;
  int row = blockIdx.x;  // grid 768: row = oc*3 + dy
  int oc = row / 3, dy = row - oc * 3;
  if (t < 192) {
#pragma unroll
    for (int k = 0; k < 4; ++k)
      *(float4*)&rowL[k][t * 4] =
          *(const float4*)(SW + (size_t)k * 589824 + (size_t)row * 768 + t * 4);
  }
  float att[8][4];
#pragma unroll
  for (int b = 0; b < 8; ++b)
#pragma unroll
    for (int k = 0; k < 4; ++k)
      att[b][k] = 0.5f / (1.f + expf(-ka[b * 4 + k]));
  __syncthreads();
  int icb = t >> 4, i = t & 15;
#pragma unroll
  for (int dx = 0; dx < 3; ++dx) {
    int col = icb * 48 + dx + 3 * i;
    float v0 = rowL[0][col], v1 = rowL[1][col], v2 = rowL[2][col],
          v3 = rowL[3][col];
    int s = dy * 3 + dx;
#pragma unroll
    for (int b = 0; b < 8; ++b) {
      float v = att[b][0] * v0 + att[b][1] * v1 + att[b][2] * v2 +
                att[b][3] * v3;
      wBF[(((size_t)(b * 16 + icb) * 9 + s) * 256 + oc) * 16 + i] =
          (unsigned short)f2bf(v);
    }
  }
}

// ---------------- conv v9: granule LDS layout (16B-aligned, no-conflict) -
// r4 post-mortem: 40B site stride made odd-site short8 reads 8B-aligned ->
// HW splits misaligned ds_read_b128 -> LDS time ~2x (dur 50->82). Fix:
// layout [row 4][icg 2][66 px][16B granule]; granule = 8 bf16 (one ic
// octet at one px). Reads: lane n -> granule ((row*2+half)*66 + n+dx),
// consecutive lanes = consecutive granules: 16B-aligned, conflict-free.
// Writes: b64 at word 4(1+px4+16pp)+(w&1)*2: only px4 vs px4+8 alias ->
// 2-way (free). Keeps r4's XCD swizzle (FETCH 69->21MB confirmed) + ring9
// + lgkm barrier + scalar 64B-coalesced x loads.
__global__ __launch_bounds__(256, 2) void conv_mfma_kernel(
    const float* __restrict__ x, const unsigned short* __restrict__ wBF,
    float* __restrict__ out) {
  __shared__ __align__(16) unsigned char ldsX[2][4 * 2 * 66 * 16];
  int t = threadIdx.x;
  // XCD swizzle: hw round-robins consecutive blockIdx across 8 XCDs.
  int orig = blockIdx.x;  // grid 512
  int xcd = orig & 7, seq = orig >> 3;
  int slice = xcd * 2 + (seq >> 5);  // = b*2 + oct; XCD x owns b = x
  int pxt = seq & 31;
  int b = slice >> 1, oct = slice & 1;
  int py0 = pxt * 2, oc0 = oct * 128;
  int lane = t & 63, w = t >> 6;
  int ocq = w >> 1, pxq = w & 1;
  int n = lane & 31, half = lane >> 5;

  // zero halo granules (px sites 0 and 65; all rows/icg) in both buffers
  if (t < 128) {
    int buf = t >> 6, rem = t & 63;
    int idx = rem >> 2, word = rem & 3;  // 16 sites x 4 words
    int r = idx >> 2, icg = (idx >> 1) & 1, c = (idx & 1) ? 65 : 0;
    *(unsigned int*)(&ldsX[buf][(((r * 2 + icg) * 66) + c) * 16 + word * 4]) =
        0u;
  }

  f32x16 acc[2][2];
#pragma unroll
  for (int i = 0; i < 2; ++i)
#pragma unroll
    for (int j = 0; j < 2; ++j)
#pragma unroll
      for (int r = 0; r < 16; ++r) acc[i][j][r] = 0.f;

  // staging role: thread owns ic w*4..w*4+3, row sub, px {px4+16pp}
  int px4 = lane & 15, sub = lane >> 4;
  int iy = py0 - 1 + sub;
  bool valid = (iy >= 0 && iy < 64);
  const float* xpb =
      x + (((size_t)(b * NC + w * 4)) * 64 + (valid ? iy : 0)) * 64 + px4;
  // write base: granule ((sub*2 + w>>1)*66 + 1 + px4), byte (w&1)*8
  int xwbase = (((sub * 2 + (w >> 1)) * 66) + 1 + px4) * 16 + (w & 1) * 8;
  unsigned char* xw0 = (unsigned char*)&ldsX[0][0] + xwbase;
  unsigned char* xw1 = (unsigned char*)&ldsX[1][0] + xwbase;

  float a[4][4];  // [ic j][pp]
#pragma unroll
  for (int j = 0; j < 4; ++j)
#pragma unroll
    for (int pp = 0; pp < 4; ++pp) a[j][pp] = 0.f;
  if (valid) {
#pragma unroll
    for (int j = 0; j < 4; ++j) {
      const float* pj = xpb + (size_t)j * 4096;
#pragma unroll
      for (int pp = 0; pp < 4; ++pp) a[j][pp] = pj[pp * 16];
    }
  }

  // A-frag ring (depth 9 = one full icb lookahead), layout [b][step][oc][16]
  const uint4* wg4 = (const uint4*)wBF;
  size_t abase =
      (size_t)b * 144 * 512 + (size_t)(oc0 + ocq * 64 + n) * 2 + half;
  U4S8 pf[9][2];
#pragma unroll
  for (int i = 0; i < 9; ++i) {
    pf[i][0].u4 = wg4[abase + (size_t)i * 512];
    pf[i][1].u4 = wg4[abase + (size_t)i * 512 + 64];
  }

  // prologue: stage icb 0 into buf 0 (pp spans px at stride 16 granules)
#pragma unroll
  for (int pp = 0; pp < 4; ++pp) {
    uint2 wv;
    wv.x = f2bf(a[0][pp]) | (f2bf(a[1][pp]) << 16);
    wv.y = f2bf(a[2][pp]) | (f2bf(a[3][pp]) << 16);
    *(uint2*)(xw0 + pp * 256) = wv;  // 16 granules * 16B
  }
  barrier_lgkm();

  for (int icb = 0; icb < 16; ++icb) {
    // issue next x-tile loads (16 coalesced dwords: 64B per 16-lane group)
#pragma unroll
    for (int j = 0; j < 4; ++j)
#pragma unroll
      for (int pp = 0; pp < 4; ++pp) a[j][pp] = 0.f;
    if (icb < 15 && valid) {
      const float* p0 = xpb + (size_t)(icb + 1) * 16 * 4096;
#pragma unroll
      for (int j = 0; j < 4; ++j) {
        const float* pj = p0 + (size_t)j * 4096;
#pragma unroll
        for (int pp = 0; pp < 4; ++pp) a[j][pp] = pj[pp * 16];
      }
    }
    const unsigned char* bufR = &ldsX[icb & 1][0];
#pragma unroll
    for (int s = 0; s < 9; ++s) {
      int step = icb * 9 + s;
      int dy = s / 3, dx = s - dy * 3;
      // granule ((pxq+dy)*2 + half)*66 + n + dx ; B1 at +32 granules
      const unsigned char* bb =
          bufR + ((((pxq + dy) * 2 + half) * 66) + n + dx) * 16;
      short8 B0 = *(const short8*)bb;
      short8 B1 = *(const short8*)(bb + 512);
      acc[0][0] = __builtin_amdgcn_mfma_f32_32x32x16_bf16(pf[s][0].s8, B0,
                                                          acc[0][0], 0, 0, 0);
      acc[0][1] = __builtin_amdgcn_mfma_f32_32x32x16_bf16(pf[s][0].s8, B1,
                                                          acc[0][1], 0, 0, 0);
      acc[1][0] = __builtin_amdgcn_mfma_f32_32x32x16_bf16(pf[s][1].s8, B0,
                                                          acc[1][0], 0, 0, 0);
      acc[1][1] = __builtin_amdgcn_mfma_f32_32x32x16_bf16(pf[s][1].s8, B1,
                                                          acc[1][1], 0, 0, 0);
      if (icb < 15) {  // refill ring slot s for next icb (WAR after mfma)
        pf[s][0].u4 = wg4[abase + (size_t)(step + 9) * 512];
        pf[s][1].u4 = wg4[abase + (size_t)(step + 9) * 512 + 64];
      }
    }
    if (icb < 15) {  // convert + write next tile into other buffer
      unsigned char* xw = (icb & 1) ? xw0 : xw1;
#pragma unroll
      for (int pp = 0; pp < 4; ++pp) {
        uint2 wv;
        wv.x = f2bf(a[0][pp]) | (f2bf(a[1][pp]) << 16);
        wv.y = f2bf(a[2][pp]) | (f2bf(a[3][pp]) << 16);
        *(uint2*)(xw + pp * 256) = wv;
      }
    }
    barrier_lgkm();
  }

  int py = py0 + pxq;
#pragma unroll
  for (int osub = 0; osub < 2; ++osub)
#pragma unroll
    for (int psub = 0; psub < 2; ++psub) {
      int OC = oc0 + ocq * 64 + osub * 32 + 4 * half;
      int pxc = psub * 32 + n;
      float* op = out + (((size_t)(b * NC + OC)) * 64 + py) * 64 + pxc;
#pragma unroll
      for (int reg = 0; reg < 16; ++reg) {
        int ocm = (reg & 3) + 8 * (reg >> 2);
        op[(size_t)ocm * 4096] = acc[osub][psub][reg];
      }
    }
}

extern "C" void kernel_launch(void* const* d_in, const int* in_sizes, int n_in,
                              void* d_out, int out_size, void* d_ws,
                              size_t ws_size, hipStream_t stream) {
  const float* x = (const float*)d_in[0];
  const float* dw = (const float*)d_in[1];
  const float* ka = (const float*)d_in[2];
  const int* fh = (const int*)d_in[3];
  const int* fw = (const int*)d_in[4];
  float* out = (float*)d_out;
  unsigned int* ws = (unsigned int*)d_ws;
  const unsigned short* specB = (const unsigned short*)d_ws;
  const unsigned short* Atw = (const unsigned short*)((char*)d_ws + 6291456);
  unsigned short* Ya = (unsigned short*)((char*)d_ws + 11010048);
  const unsigned short* T = (const unsigned short*)((char*)d_ws + 15925248);
  float* SW = (float*)d_ws;
  unsigned short* wBF = (unsigned short*)((char*)d_ws + WBF_BYTE);

  hipLaunchKernelGGL(prep_kernel, dim3(11364), dim3(256), 0, stream, dw, fh,
                     fw, ws);
  hipLaunchKernelGGL(fftA_kernel, dim3(6, 7, 8), dim3(256), 0, stream, Atw,
                     specB, Ya);
  hipLaunchKernelGGL(fftB_kernel, dim3(6, 12, KNUM), dim3(256), 0, stream, Ya,
                     T, SW);
  hipLaunchKernelGGL(wprep_kernel, dim3(768), dim3(256), 0, stream, ka, SW,
                     wBF);
  hipLaunchKernelGGL(conv_mfma_kernel, dim3(512), dim3(256), 0, stream, x,
                     wBF, out);
}

// Round 6
// 190.619 us; speedup vs baseline: 1.1746x; 1.0210x over previous
//
#include <hip/hip_runtime.h>
#include <math.h>

#define D1 768
#define D2R 385
#define NF 295680   // 768*385
#define KNUM 4
#define NB 8
#define NC 256
#define TWOPI_768 0.008181230868723419f
#define INV768 0.0013020833333333333f

// ---------------- ws layout (bytes) --------------------------------------
// specB  bf16 [4][448 c-rows][1536 k]   @ 0          (6,291,456 B)  B^T stage A
// Atw    bf16 [2][768 m][1536 k]        @ 6,291,456  (4,718,592 B)  A stage A
// Ya     bf16 [4][768 m][800 k]         @ 11,010,048 (4,915,200 B)  A stage B
// T      bf16 [768 n][800 k]            @ 15,925,248 (1,228,800 B)  B^T stage B
// SW     f32  [4][768][768]             @ 0          (9,437,184 B)  overlays specB+Atw (dead)
// wBF    bf16 [8][16][9][256][16]       @ 9,437,184  (9,437,184 B)  overlays Ya+T (dead)
#define ATW_U32 1572864u
#define YA_U32 2752512u
#define T_U32 3981312u
#define SPECB_K_U32 344064u  // 448*768 uints per k
#define WBF_BYTE 9437184u

typedef __attribute__((ext_vector_type(8))) short short8;
typedef __attribute__((ext_vector_type(16))) float f32x16;
union U4S8 { unsigned int u[4]; uint4 u4; short8 s8; };

static __device__ __forceinline__ unsigned int f2bf(float f) {
  unsigned int u = __float_as_uint(f);
  return (u + 0x7fffu + ((u >> 16) & 1u)) >> 16;  // RNE, no NaN inputs
}

// hw sin/cos: v_sin_f32/v_cos_f32 take REVOLUTIONS; idx in [0,768) -> idx/768
static __device__ __forceinline__ void sincos_rev768(int idx, float* s,
                                                     float* c) {
  float rev = (float)idx * INV768;
  *s = __builtin_amdgcn_sinf(rev);
  *c = __builtin_amdgcn_cosf(rev);
}

// raw barrier: LDS-drain only; register-dest vmem loads stay in flight.
static __device__ __forceinline__ void barrier_lgkm() {
  asm volatile("s_waitcnt lgkmcnt(0)" ::: "memory");
  __builtin_amdgcn_sched_barrier(0);
  __builtin_amdgcn_s_barrier();
  __builtin_amdgcn_sched_barrier(0);
}

// ---------------- prep: scatter + twiddle matrices + zero pads -----------
__global__ __launch_bounds__(256) void prep_kernel(
    const float* __restrict__ dw, const int* __restrict__ fh,
    const int* __restrict__ fw, unsigned int* __restrict__ ws) {
  long i = (long)blockIdx.x * 256 + threadIdx.x;  // grid 11364
  if (i < 1182720) {  // scatter: dft_weight -> bf16 B^T spectrum
    int k = (int)(i / NF);
    int r = (int)(i - (long)k * NF);
    const float2 v = ((const float2*)dw)[i];
    int h = fh[r], c = fw[r];
    ws[(size_t)k * SPECB_K_U32 + (size_t)c * 768 + h] =
        f2bf(v.x) | (f2bf(v.y) << 16);
    return;
  }
  long j = i - 1182720;
  if (j < 1179648) {  // Atw: A_re/A_im [768 m][1536 k=2h]
    int ri = (int)(j / 589824);
    int rem = (int)(j - (long)ri * 589824);
    int m = rem / 768, h = rem - (rem / 768) * 768;
    int idx = (h * m) % 768;
    float s, c;
    sincos_rev768(idx, &s, &c);
    unsigned lo, hi;
    if (ri == 0) { lo = f2bf(c); hi = f2bf(-s); }
    else         { lo = f2bf(s); hi = f2bf(c); }
    ws[ATW_U32 + j] = lo | (hi << 16);
  } else if (j < 1486848) {  // T^T [768 n][800 k=2c]
    long p = j - 1179648;
    int n = (int)(p / 400), cc = (int)(p - (p / 400) * 400);
    unsigned v = 0;
    if (cc <= 384) {
      float wgt = (cc == 0 || cc == 384) ? 1.6954210069444445e-6f
                                         : 3.390842013888889e-6f;
      int idx = (cc * n) % 768;
      float s, c;
      sincos_rev768(idx, &s, &c);
      v = f2bf(wgt * c) | (f2bf(-wgt * s) << 16);
    }
    ws[T_U32 + (size_t)n * 400 + cc] = v;
  } else if (j < 1680384) {  // specB zero rows 385..447
    long p = j - 1486848;
    int k = (int)(p / 48384);
    long r = p - (long)k * 48384;
    int row = 385 + (int)(r / 768);
    int col = (int)(r - (r / 768) * 768);
    ws[(size_t)k * SPECB_K_U32 + (size_t)row * 768 + col] = 0u;
  } else if (j < 1726464) {  // Ya zero cols 770..799
    long p = j - 1680384;
    int k = (int)(p / 11520);
    long r = p - (long)k * 11520;
    int m = (int)(r / 15), jj = (int)(r - (r / 15) * 15);
    ws[YA_U32 + (size_t)k * 307200 + (size_t)m * 400 + 385 + jj] = 0u;
  }
}

// ---------------- fftA v3: 2-deep reg prefetch + lgkm-only barrier -------
// r5 ledger post-mortem: __syncthreads per kb drains vmcnt(0) of the loads
// issued THIS iter -> full L2/L3 latency serialized into each of 48 iters
// at ~1.3 blocks/CU. Fix: named reg sets E/O hold tiles kb+1/kb+2; loads
// issued ~1.5 iters before their ds_write; barrier waits lgkm only.
#define FFTA_LOAD(d0, d1, db, kb)                                         \
  d0 = *(const uint4*)(Ag + (size_t)rowA * 1536 + (kb) * 32 + qa * 16);   \
  d1 = *(const uint4*)(Ag + (size_t)rowA * 1536 + (kb) * 32 + qa * 16 + 8); \
  db = *(const uint4*)(Bg + (size_t)rowB * 1536 + (kb) * 32 + qb * 8);
#define FFT_WRITE(buf, s0, s1, sb)                                        \
  *(uint4*)&Al[buf][wrA] = s0;                                            \
  *(uint4*)&Al[buf][wrA + 8] = s1;                                        \
  *(uint4*)&Bl[buf][wrB] = sb;
#define FFT_COMPUTE(buf)                                                  \
  {                                                                       \
    const unsigned short* Ab = Al[buf];                                   \
    const unsigned short* Bb = Bl[buf];                                   \
    _Pragma("unroll") for (int kk2 = 0; kk2 < 2; ++kk2) {                 \
      short8 b8 = *(const short8*)&Bb[bo + kk2 * 16];                     \
      short8 a80 = *(const short8*)&Ab[ao0 + kk2 * 16];                   \
      short8 a81 = *(const short8*)&Ab[ao1 + kk2 * 16];                   \
      acc[0] =                                                            \
          __builtin_amdgcn_mfma_f32_32x32x16_bf16(a80, b8, acc[0], 0, 0, 0); \
      acc[1] =                                                            \
          __builtin_amdgcn_mfma_f32_32x32x16_bf16(a81, b8, acc[1], 0, 0, 0); \
    }                                                                     \
  }

__global__ __launch_bounds__(256) void fftA_kernel(
    const unsigned short* __restrict__ Atw,
    const unsigned short* __restrict__ specB,
    unsigned short* __restrict__ Ya) {
  __shared__ __align__(16) unsigned short Al[2][128 * 40], Bl[2][64 * 40];
  int t = threadIdx.x;
  int mt = blockIdx.x, nt = blockIdx.y, z = blockIdx.z;
  int ri = z & 1, k = z >> 1;
  const unsigned short* Ag =
      Atw + (size_t)ri * 1179648 + (size_t)(mt * 128) * 1536;
  const unsigned short* Bg =
      specB + (size_t)k * 688128 + (size_t)(nt * 64) * 1536;
  int rowA = t >> 1, qa = t & 1;  // A: 128 rows x 2 chunks of 16 shorts
  int rowB = t >> 2, qb = t & 3;  // B: 64 rows x 4 chunks of 8 shorts
  int lane = t & 63, w = t >> 6;
  int mq = w & 1, nq = w >> 1;
  int lm = lane & 31, half = lane >> 5;
  int wrA = rowA * 40 + qa * 16;
  int wrB = rowB * 40 + qb * 8;
  int ao0 = (mq * 64 + lm) * 40 + half * 8;
  int ao1 = (mq * 64 + 32 + lm) * 40 + half * 8;
  int bo = (nq * 32 + lm) * 40 + half * 8;

  f32x16 acc[2];
#pragma unroll
  for (int i = 0; i < 2; ++i)
#pragma unroll
    for (int r = 0; r < 16; ++r) acc[i][r] = 0.f;

  uint4 eA0, eA1, eB, oA0, oA1, oB;
  FFTA_LOAD(eA0, eA1, eB, 0)   // tile 0 -> E
  FFTA_LOAD(oA0, oA1, oB, 1)   // tile 1 -> O (stays in flight)
  FFT_WRITE(0, eA0, eA1, eB)   // auto vmcnt waits E only
  barrier_lgkm();

  const int NK = 48;
  for (int kb = 0; kb < NK; kb += 2) {
    // even iter: compute tile kb (buf0); write buf1 <- O (tile kb+1)
    if (kb + 2 < NK) { FFTA_LOAD(eA0, eA1, eB, kb + 2) }
    FFT_COMPUTE(0)
    if (kb + 1 < NK) { FFT_WRITE(1, oA0, oA1, oB) }
    barrier_lgkm();
    if (kb + 1 < NK) {
      // odd iter: compute tile kb+1 (buf1); write buf0 <- E (tile kb+2)
      if (kb + 3 < NK) { FFTA_LOAD(oA0, oA1, oB, kb + 3) }
      FFT_COMPUTE(1)
      if (kb + 2 < NK) { FFT_WRITE(0, eA0, eA1, eB) }
      barrier_lgkm();
    }
  }

  int c = nt * 64 + nq * 32 + lm;
  if (c < D2R) {
    unsigned short* Yk = Ya + (size_t)k * 614400;
#pragma unroll
    for (int i = 0; i < 2; ++i) {
      int mb = mt * 128 + mq * 64 + i * 32 + 4 * half;
#pragma unroll
      for (int reg = 0; reg < 16; ++reg) {
        int m = mb + (reg & 3) + 8 * (reg >> 2);
        Yk[(size_t)m * 800 + 2 * c + ri] = (unsigned short)f2bf(acc[i][reg]);
      }
    }
  }
}

// ---------------- fftB v3: same 2-deep pipeline, K=800 (25 iters) --------
#define FFTB_LOAD(d0, d1, db, kb)                                         \
  d0 = *(const uint4*)(Ag + (size_t)rowA * 800 + (kb) * 32 + qa * 16);    \
  d1 = *(const uint4*)(Ag + (size_t)rowA * 800 + (kb) * 32 + qa * 16 + 8); \
  db = *(const uint4*)(Bg + (size_t)rowB * 800 + (kb) * 32 + qb * 8);

__global__ __launch_bounds__(256) void fftB_kernel(
    const unsigned short* __restrict__ Ya, const unsigned short* __restrict__ T,
    float* __restrict__ SW) {
  __shared__ __align__(16) unsigned short Al[2][128 * 40], Bl[2][64 * 40];
  int t = threadIdx.x;
  int mt = blockIdx.x, nt = blockIdx.y, k = blockIdx.z;
  const unsigned short* Ag = Ya + (size_t)k * 614400 + (size_t)(mt * 128) * 800;
  const unsigned short* Bg = T + (size_t)(nt * 64) * 800;
  int rowA = t >> 1, qa = t & 1;
  int rowB = t >> 2, qb = t & 3;
  int lane = t & 63, w = t >> 6;
  int mq = w & 1, nq = w >> 1;
  int lm = lane & 31, half = lane >> 5;
  int wrA = rowA * 40 + qa * 16;
  int wrB = rowB * 40 + qb * 8;
  int ao0 = (mq * 64 + lm) * 40 + half * 8;
  int ao1 = (mq * 64 + 32 + lm) * 40 + half * 8;
  int bo = (nq * 32 + lm) * 40 + half * 8;

  f32x16 acc[2];
#pragma unroll
  for (int i = 0; i < 2; ++i)
#pragma unroll
    for (int r = 0; r < 16; ++r) acc[i][r] = 0.f;

  uint4 eA0, eA1, eB, oA0, oA1, oB;
  FFTB_LOAD(eA0, eA1, eB, 0)
  FFTB_LOAD(oA0, oA1, oB, 1)
  FFT_WRITE(0, eA0, eA1, eB)
  barrier_lgkm();

  const int NK = 25;
  for (int kb = 0; kb < NK; kb += 2) {
    if (kb + 2 < NK) { FFTB_LOAD(eA0, eA1, eB, kb + 2) }
    FFT_COMPUTE(0)
    if (kb + 1 < NK) { FFT_WRITE(1, oA0, oA1, oB) }
    barrier_lgkm();
    if (kb + 1 < NK) {
      if (kb + 3 < NK) { FFTB_LOAD(oA0, oA1, oB, kb + 3) }
      FFT_COMPUTE(1)
      if (kb + 2 < NK) { FFT_WRITE(0, eA0, eA1, eB) }
      barrier_lgkm();
    }
  }

  float* SWk = SW + (size_t)k * 589824;
  int n = nt * 64 + nq * 32 + lm;
#pragma unroll
  for (int i = 0; i < 2; ++i) {
    int mb = mt * 128 + mq * 64 + i * 32 + 4 * half;
#pragma unroll
    for (int reg = 0; reg < 16; ++reg) {
      int m = mb + (reg & 3) + 8 * (reg >> 2);
      SWk[(size_t)m * 768 + n] = acc[i][reg];
    }
  }
}

// ---------------- wprep v2: 1 block per SW row, LDS-staged coalesced -----
__global__ __launch_bounds__(256) void wprep_kernel(
    const float* __restrict__ ka, const float* __restrict__ SW,
    unsigned short* __restrict__ wBF) {
  __shared__ float rowL[4][768];
  int t = threadIdx.x;
  int row = blockIdx.x;  // grid 768: row = oc*3 + dy
  int oc = row / 3, dy = row - oc * 3;
  if (t < 192) {
#pragma unroll
    for (int k = 0; k < 4; ++k)
      *(float4*)&rowL[k][t * 4] =
          *(const float4*)(SW + (size_t)k * 589824 + (size_t)row * 768 + t * 4);
  }
  float att[8][4];
#pragma unroll
  for (int b = 0; b < 8; ++b)
#pragma unroll
    for (int k = 0; k < 4; ++k)
      att[b][k] = 0.5f / (1.f + expf(-ka[b * 4 + k]));
  __syncthreads();
  int icb = t >> 4, i = t & 15;
#pragma unroll
  for (int dx = 0; dx < 3; ++dx) {
    int col = icb * 48 + dx + 3 * i;
    float v0 = rowL[0][col], v1 = rowL[1][col], v2 = rowL[2][col],
          v3 = rowL[3][col];
    int s = dy * 3 + dx;
#pragma unroll
    for (int b = 0; b < 8; ++b) {
      float v = att[b][0] * v0 + att[b][1] * v1 + att[b][2] * v2 +
                att[b][3] * v3;
      wBF[(((size_t)(b * 16 + icb) * 9 + s) * 256 + oc) * 16 + i] =
          (unsigned short)f2bf(v);
    }
  }
}

// ---------------- conv v9: granule LDS layout (16B-aligned, no-conflict) -
__global__ __launch_bounds__(256, 2) void conv_mfma_kernel(
    const float* __restrict__ x, const unsigned short* __restrict__ wBF,
    float* __restrict__ out) {
  __shared__ __align__(16) unsigned char ldsX[2][4 * 2 * 66 * 16];
  int t = threadIdx.x;
  // XCD swizzle: hw round-robins consecutive blockIdx across 8 XCDs.
  int orig = blockIdx.x;  // grid 512
  int xcd = orig & 7, seq = orig >> 3;
  int slice = xcd * 2 + (seq >> 5);  // = b*2 + oct; XCD x owns b = x
  int pxt = seq & 31;
  int b = slice >> 1, oct = slice & 1;
  int py0 = pxt * 2, oc0 = oct * 128;
  int lane = t & 63, w = t >> 6;
  int ocq = w >> 1, pxq = w & 1;
  int n = lane & 31, half = lane >> 5;

  // zero halo granules (px sites 0 and 65; all rows/icg) in both buffers
  if (t < 128) {
    int buf = t >> 6, rem = t & 63;
    int idx = rem >> 2, word = rem & 3;  // 16 sites x 4 words
    int r = idx >> 2, icg = (idx >> 1) & 1, c = (idx & 1) ? 65 : 0;
    *(unsigned int*)(&ldsX[buf][(((r * 2 + icg) * 66) + c) * 16 + word * 4]) =
        0u;
  }

  f32x16 acc[2][2];
#pragma unroll
  for (int i = 0; i < 2; ++i)
#pragma unroll
    for (int j = 0; j < 2; ++j)
#pragma unroll
      for (int r = 0; r < 16; ++r) acc[i][j][r] = 0.f;

  // staging role: thread owns ic w*4..w*4+3, row sub, px {px4+16pp}
  int px4 = lane & 15, sub = lane >> 4;
  int iy = py0 - 1 + sub;
  bool valid = (iy >= 0 && iy < 64);
  const float* xpb =
      x + (((size_t)(b * NC + w * 4)) * 64 + (valid ? iy : 0)) * 64 + px4;
  // write base: granule ((sub*2 + w>>1)*66 + 1 + px4), byte (w&1)*8
  int xwbase = (((sub * 2 + (w >> 1)) * 66) + 1 + px4) * 16 + (w & 1) * 8;
  unsigned char* xw0 = (unsigned char*)&ldsX[0][0] + xwbase;
  unsigned char* xw1 = (unsigned char*)&ldsX[1][0] + xwbase;

  float a[4][4];  // [ic j][pp]
#pragma unroll
  for (int j = 0; j < 4; ++j)
#pragma unroll
    for (int pp = 0; pp < 4; ++pp) a[j][pp] = 0.f;
  if (valid) {
#pragma unroll
    for (int j = 0; j < 4; ++j) {
      const float* pj = xpb + (size_t)j * 4096;
#pragma unroll
      for (int pp = 0; pp < 4; ++pp) a[j][pp] = pj[pp * 16];
    }
  }

  // A-frag ring (depth 9 = one full icb lookahead), layout [b][step][oc][16]
  const uint4* wg4 = (const uint4*)wBF;
  size_t abase =
      (size_t)b * 144 * 512 + (size_t)(oc0 + ocq * 64 + n) * 2 + half;
  U4S8 pf[9][2];
#pragma unroll
  for (int i = 0; i < 9; ++i) {
    pf[i][0].u4 = wg4[abase + (size_t)i * 512];
    pf[i][1].u4 = wg4[abase + (size_t)i * 512 + 64];
  }

  // prologue: stage icb 0 into buf 0 (pp spans px at stride 16 granules)
#pragma unroll
  for (int pp = 0; pp < 4; ++pp) {
    uint2 wv;
    wv.x = f2bf(a[0][pp]) | (f2bf(a[1][pp]) << 16);
    wv.y = f2bf(a[2][pp]) | (f2bf(a[3][pp]) << 16);
    *(uint2*)(xw0 + pp * 256) = wv;  // 16 granules * 16B
  }
  barrier_lgkm();

  for (int icb = 0; icb < 16; ++icb) {
    // issue next x-tile loads (16 coalesced dwords: 64B per 16-lane group)
#pragma unroll
    for (int j = 0; j < 4; ++j)
#pragma unroll
      for (int pp = 0; pp < 4; ++pp) a[j][pp] = 0.f;
    if (icb < 15 && valid) {
      const float* p0 = xpb + (size_t)(icb + 1) * 16 * 4096;
#pragma unroll
      for (int j = 0; j < 4; ++j) {
        const float* pj = p0 + (size_t)j * 4096;
#pragma unroll
        for (int pp = 0; pp < 4; ++pp) a[j][pp] = pj[pp * 16];
      }
    }
    const unsigned char* bufR = &ldsX[icb & 1][0];
#pragma unroll
    for (int s = 0; s < 9; ++s) {
      int step = icb * 9 + s;
      int dy = s / 3, dx = s - dy * 3;
      // granule ((pxq+dy)*2 + half)*66 + n + dx ; B1 at +32 granules
      const unsigned char* bb =
          bufR + ((((pxq + dy) * 2 + half) * 66) + n + dx) * 16;
      short8 B0 = *(const short8*)bb;
      short8 B1 = *(const short8*)(bb + 512);
      acc[0][0] = __builtin_amdgcn_mfma_f32_32x32x16_bf16(pf[s][0].s8, B0,
                                                          acc[0][0], 0, 0, 0);
      acc[0][1] = __builtin_amdgcn_mfma_f32_32x32x16_bf16(pf[s][0].s8, B1,
                                                          acc[0][1], 0, 0, 0);
      acc[1][0] = __builtin_amdgcn_mfma_f32_32x32x16_bf16(pf[s][1].s8, B0,
                                                          acc[1][0], 0, 0, 0);
      acc[1][1] = __builtin_amdgcn_mfma_f32_32x32x16_bf16(pf[s][1].s8, B1,
                                                          acc[1][1], 0, 0, 0);
      if (icb < 15) {  // refill ring slot s for next icb (WAR after mfma)
        pf[s][0].u4 = wg4[abase + (size_t)(step + 9) * 512];
        pf[s][1].u4 = wg4[abase + (size_t)(step + 9) * 512 + 64];
      }
    }
    if (icb < 15) {  // convert + write next tile into other buffer
      unsigned char* xw = (icb & 1) ? xw0 : xw1;
#pragma unroll
      for (int pp = 0; pp < 4; ++pp) {
        uint2 wv;
        wv.x = f2bf(a[0][pp]) | (f2bf(a[1][pp]) << 16);
        wv.y = f2bf(a[2][pp]) | (f2bf(a[3][pp]) << 16);
        *(uint2*)(xw + pp * 256) = wv;
      }
    }
    barrier_lgkm();
  }

  int py = py0 + pxq;
#pragma unroll
  for (int osub = 0; osub < 2; ++osub)
#pragma unroll
    for (int psub = 0; psub < 2; ++psub) {
      int OC = oc0 + ocq * 64 + osub * 32 + 4 * half;
      int pxc = psub * 32 + n;
      float* op = out + (((size_t)(b * NC + OC)) * 64 + py) * 64 + pxc;
#pragma unroll
      for (int reg = 0; reg < 16; ++reg) {
        int ocm = (reg & 3) + 8 * (reg >> 2);
        op[(size_t)ocm * 4096] = acc[osub][psub][reg];
      }
    }
}

extern "C" void kernel_launch(void* const* d_in, const int* in_sizes, int n_in,
                              void* d_out, int out_size, void* d_ws,
                              size_t ws_size, hipStream_t stream) {
  const float* x = (const float*)d_in[0];
  const float* dw = (const float*)d_in[1];
  const float* ka = (const float*)d_in[2];
  const int* fh = (const int*)d_in[3];
  const int* fw = (const int*)d_in[4];
  float* out = (float*)d_out;
  unsigned int* ws = (unsigned int*)d_ws;
  const unsigned short* specB = (const unsigned short*)d_ws;
  const unsigned short* Atw = (const unsigned short*)((char*)d_ws + 6291456);
  unsigned short* Ya = (unsigned short*)((char*)d_ws + 11010048);
  const unsigned short* T = (const unsigned short*)((char*)d_ws + 15925248);
  float* SW = (float*)d_ws;
  unsigned short* wBF = (unsigned short*)((char*)d_ws + WBF_BYTE);

  hipLaunchKernelGGL(prep_kernel, dim3(11364), dim3(256), 0, stream, dw, fh,
                     fw, ws);
  hipLaunchKernelGGL(fftA_kernel, dim3(6, 7, 8), dim3(256), 0, stream, Atw,
                     specB, Ya);
  hipLaunchKernelGGL(fftB_kernel, dim3(6, 12, KNUM), dim3(256), 0, stream, Ya,
                     T, SW);
  hipLaunchKernelGGL(wprep_kernel, dim3(768), dim3(256), 0, stream, ka, SW,
                     wBF);
  hipLaunchKernelGGL(conv_mfma_kernel, dim3(512), dim3(256), 0, stream, x,
                     wBF, out);
}

// Round 7
// 184.623 us; speedup vs baseline: 1.2127x; 1.0325x over previous
//
#include <hip/hip_runtime.h>
#include <math.h>

#define D1 768
#define D2R 385
#define NF 295680   // 768*385
#define KNUM 4
#define NB 8
#define NC 256
#define TWOPI_768 0.008181230868723419f
#define INV768 0.0013020833333333333f

// ---------------- ws layout (bytes) --------------------------------------
// specB  bf16 [4][448 c-rows][1536 k]   @ 0          (6,291,456 B)  B^T stage A
// Atw    bf16 [2][768 m][1536 k]        @ 6,291,456  (4,718,592 B)  A stage A
// Ya     bf16 [4][768 m][800 k]         @ 11,010,048 (4,915,200 B)  A stage B
// T      bf16 [768 n][800 k]            @ 15,925,248 (1,228,800 B)  B^T stage B
// SW     f32  [4][768][768]             @ 0          (9,437,184 B)  overlays specB+Atw (dead)
// wBF    bf16 [8][16][9][256][16]       @ 9,437,184  (9,437,184 B)  overlays Ya+T (dead)
#define ATW_U32 1572864u
#define YA_U32 2752512u
#define T_U32 3981312u
#define SPECB_K_U32 344064u  // 448*768 uints per k
#define WBF_BYTE 9437184u

typedef __attribute__((ext_vector_type(8))) short short8;
typedef __attribute__((ext_vector_type(16))) float f32x16;
union U4S8 { unsigned int u[4]; uint4 u4; short8 s8; };

static __device__ __forceinline__ unsigned int f2bf(float f) {
  unsigned int u = __float_as_uint(f);
  return (u + 0x7fffu + ((u >> 16) & 1u)) >> 16;  // RNE, no NaN inputs
}

// hw sin/cos: v_sin_f32/v_cos_f32 take REVOLUTIONS; idx in [0,768) -> idx/768
static __device__ __forceinline__ void sincos_rev768(int idx, float* s,
                                                     float* c) {
  float rev = (float)idx * INV768;
  *s = __builtin_amdgcn_sinf(rev);
  *c = __builtin_amdgcn_cosf(rev);
}

// raw barrier: LDS-drain only; register-dest vmem loads stay in flight.
static __device__ __forceinline__ void barrier_lgkm() {
  asm volatile("s_waitcnt lgkmcnt(0)" ::: "memory");
  __builtin_amdgcn_sched_barrier(0);
  __builtin_amdgcn_s_barrier();
  __builtin_amdgcn_sched_barrier(0);
}

// ---------------- prep v2: 4 elems/thread, vectorized IO -----------------
// r6 ledger: prep was 11364 blocks x 256 threads with ~10 instrs each --
// possible dispatch/thread-count bound. Now 2841 blocks; float4/int4 reads,
// uint4 writes on 16B-aligned segments (all segment strides %4 == 0).
__global__ __launch_bounds__(256) void prep_kernel(
    const float* __restrict__ dw, const int* __restrict__ fh,
    const int* __restrict__ fw, unsigned int* __restrict__ ws) {
  int q = blockIdx.x * 256 + threadIdx.x;  // grid 2841 -> 727296 quads
  if (q < 295680) {  // scatter: 4 consecutive r of one k
    int k = q / 73920;
    int ql = q - k * 73920;  // int4 index into fh/fw
    long f2i = (long)k * NF + (long)ql * 4;
    const float4 v0 = ((const float4*)dw)[f2i >> 1];
    const float4 v1 = ((const float4*)dw)[(f2i >> 1) + 1];
    const int4 h4 = ((const int4*)fh)[ql];
    const int4 c4 = ((const int4*)fw)[ql];
    size_t kb = (size_t)k * SPECB_K_U32;
    ws[kb + (size_t)c4.x * 768 + h4.x] = f2bf(v0.x) | (f2bf(v0.y) << 16);
    ws[kb + (size_t)c4.y * 768 + h4.y] = f2bf(v0.z) | (f2bf(v0.w) << 16);
    ws[kb + (size_t)c4.z * 768 + h4.z] = f2bf(v1.x) | (f2bf(v1.y) << 16);
    ws[kb + (size_t)c4.w * 768 + h4.w] = f2bf(v1.z) | (f2bf(v1.w) << 16);
    return;
  }
  int j = q - 295680;
  if (j < 294912) {  // Atw: 4 consecutive h of one (ri,m)
    int j0 = j * 4;  // element index, %4==0
    int ri = j0 / 589824;
    int rem = j0 - ri * 589824;
    int m = rem / 768, h0 = rem - (rem / 768) * 768;
    uint4 o;
#pragma unroll
    for (int e = 0; e < 4; ++e) {
      int idx = ((h0 + e) * m) % 768;
      float s, c;
      sincos_rev768(idx, &s, &c);
      unsigned lo, hi;
      if (ri == 0) { lo = f2bf(c); hi = f2bf(-s); }
      else         { lo = f2bf(s); hi = f2bf(c); }
      ((unsigned*)&o)[e] = lo | (hi << 16);
    }
    *(uint4*)(ws + ATW_U32 + j0) = o;
  } else if (j < 371712) {  // T^T: 4 consecutive cc of one n
    int p0 = (j - 294912) * 4;
    int n = p0 / 400, cc0 = p0 - (p0 / 400) * 400;
    uint4 o;
#pragma unroll
    for (int e = 0; e < 4; ++e) {
      int cc = cc0 + e;
      unsigned v = 0;
      if (cc <= 384) {
        float wgt = (cc == 0 || cc == 384) ? 1.6954210069444445e-6f
                                           : 3.390842013888889e-6f;
        int idx = (cc * n) % 768;
        float s, c;
        sincos_rev768(idx, &s, &c);
        v = f2bf(wgt * c) | (f2bf(-wgt * s) << 16);
      }
      ((unsigned*)&o)[e] = v;
    }
    *(uint4*)(ws + T_U32 + (size_t)n * 400 + cc0) = o;
  } else if (j < 420096) {  // specB zero rows 385..447 (uint4)
    int p0 = (j - 371712) * 4;
    int k = p0 / 48384;
    int r = p0 - k * 48384;
    int row = 385 + r / 768;
    int col = r - (r / 768) * 768;
    *(uint4*)(ws + (size_t)k * SPECB_K_U32 + (size_t)row * 768 + col) =
        make_uint4(0u, 0u, 0u, 0u);
  } else if (j < 431616) {  // Ya zero cols 770..799 (scalar x4: stride 15)
    int p0 = (j - 420096) * 4;
#pragma unroll
    for (int e = 0; e < 4; ++e) {
      int p = p0 + e;
      int k = p / 11520;
      int r = p - k * 11520;
      int m = r / 15, jj = r - (r / 15) * 15;
      ws[YA_U32 + (size_t)k * 307200 + (size_t)m * 400 + 385 + jj] = 0u;
    }
  }
}

// ---------------- fftA v5: 64x64 tile + E/O pipeline, grid 672 -----------
// r6 post-mortem: pipeline alone (336 blocks = 1.3/CU) was null -- one
// iteration of reg-lookahead (~300cy) < L3 latency (~600-900cy) and
// barrier-lockstep correlates all 4 waves. 64-tile alone (r2) also null
// (vmcnt-drain barrier). Combination: 2.6 blocks/CU of independent
// pipelined blocks -> cross-block overlap hides the remaining latency.
__global__ __launch_bounds__(256) void fftA_kernel(
    const unsigned short* __restrict__ Atw,
    const unsigned short* __restrict__ specB,
    unsigned short* __restrict__ Ya) {
  __shared__ __align__(16) unsigned short Al[2][64 * 40], Bl[2][64 * 40];
  int t = threadIdx.x;
  int mt = blockIdx.x, nt = blockIdx.y, z = blockIdx.z;
  int ri = z & 1, k = z >> 1;
  const unsigned short* Ag =
      Atw + (size_t)ri * 1179648 + (size_t)(mt * 64) * 1536;
  const unsigned short* Bg =
      specB + (size_t)k * 688128 + (size_t)(nt * 64) * 1536;
  int rowS = t >> 2, q = t & 3;
  int lane = t & 63, w = t >> 6;
  int mq = w & 1, nq = w >> 1;
  int lm = lane & 31, half = lane >> 5;
  int wr = rowS * 40 + q * 8;
  int ao = (mq * 32 + lm) * 40 + half * 8;
  int bo = (nq * 32 + lm) * 40 + half * 8;

  f32x16 acc;
#pragma unroll
  for (int r = 0; r < 16; ++r) acc[r] = 0.f;

#define FA_LOAD(da, db, kb)                                              \
  da = *(const uint4*)(Ag + (size_t)rowS * 1536 + (kb) * 32 + q * 8);    \
  db = *(const uint4*)(Bg + (size_t)rowS * 1536 + (kb) * 32 + q * 8);
#define F_WRITE(buf, sa, sb)                                             \
  *(uint4*)&Al[buf][wr] = sa;                                            \
  *(uint4*)&Bl[buf][wr] = sb;
#define F_COMPUTE(buf)                                                   \
  {                                                                      \
    const unsigned short* Ab = Al[buf];                                  \
    const unsigned short* Bb = Bl[buf];                                  \
    _Pragma("unroll") for (int kk2 = 0; kk2 < 2; ++kk2) {                \
      short8 a8 = *(const short8*)&Ab[ao + kk2 * 16];                    \
      short8 b8 = *(const short8*)&Bb[bo + kk2 * 16];                    \
      acc = __builtin_amdgcn_mfma_f32_32x32x16_bf16(a8, b8, acc, 0, 0, 0); \
    }                                                                    \
  }

  uint4 eA, eB, oA, oB;
  FA_LOAD(eA, eB, 0)
  FA_LOAD(oA, oB, 1)
  F_WRITE(0, eA, eB)
  barrier_lgkm();

  const int NK = 48;
  for (int kb = 0; kb < NK; kb += 2) {
    if (kb + 2 < NK) { FA_LOAD(eA, eB, kb + 2) }
    F_COMPUTE(0)
    if (kb + 1 < NK) { F_WRITE(1, oA, oB) }
    barrier_lgkm();
    if (kb + 1 < NK) {
      if (kb + 3 < NK) { FA_LOAD(oA, oB, kb + 3) }
      F_COMPUTE(1)
      if (kb + 2 < NK) { F_WRITE(0, eA, eB) }
      barrier_lgkm();
    }
  }

  int c = nt * 64 + nq * 32 + lm;
  if (c < D2R) {
    unsigned short* Yk = Ya + (size_t)k * 614400;
    int mb = mt * 64 + mq * 32 + 4 * half;
#pragma unroll
    for (int reg = 0; reg < 16; ++reg) {
      int m = mb + (reg & 3) + 8 * (reg >> 2);
      Yk[(size_t)m * 800 + 2 * c + ri] = (unsigned short)f2bf(acc[reg]);
    }
  }
}

// ---------------- fftB v5: 64x64 tile + E/O pipeline, grid 576 -----------
__global__ __launch_bounds__(256) void fftB_kernel(
    const unsigned short* __restrict__ Ya, const unsigned short* __restrict__ T,
    float* __restrict__ SW) {
  __shared__ __align__(16) unsigned short Al[2][64 * 40], Bl[2][64 * 40];
  int t = threadIdx.x;
  int mt = blockIdx.x, nt = blockIdx.y, k = blockIdx.z;
  const unsigned short* Ag = Ya + (size_t)k * 614400 + (size_t)(mt * 64) * 800;
  const unsigned short* Bg = T + (size_t)(nt * 64) * 800;
  int rowS = t >> 2, q = t & 3;
  int lane = t & 63, w = t >> 6;
  int mq = w & 1, nq = w >> 1;
  int lm = lane & 31, half = lane >> 5;
  int wr = rowS * 40 + q * 8;
  int ao = (mq * 32 + lm) * 40 + half * 8;
  int bo = (nq * 32 + lm) * 40 + half * 8;

  f32x16 acc;
#pragma unroll
  for (int r = 0; r < 16; ++r) acc[r] = 0.f;

#define FB_LOAD(da, db, kb)                                             \
  da = *(const uint4*)(Ag + (size_t)rowS * 800 + (kb) * 32 + q * 8);    \
  db = *(const uint4*)(Bg + (size_t)rowS * 800 + (kb) * 32 + q * 8);

  uint4 eA, eB, oA, oB;
  FB_LOAD(eA, eB, 0)
  FB_LOAD(oA, oB, 1)
  F_WRITE(0, eA, eB)
  barrier_lgkm();

  const int NK = 25;
  for (int kb = 0; kb < NK; kb += 2) {
    if (kb + 2 < NK) { FB_LOAD(eA, eB, kb + 2) }
    F_COMPUTE(0)
    if (kb + 1 < NK) { F_WRITE(1, oA, oB) }
    barrier_lgkm();
    if (kb + 1 < NK) {
      if (kb + 3 < NK) { FB_LOAD(oA, oB, kb + 3) }
      F_COMPUTE(1)
      if (kb + 2 < NK) { F_WRITE(0, eA, eB) }
      barrier_lgkm();
    }
  }

  float* SWk = SW + (size_t)k * 589824;
  int n = nt * 64 + nq * 32 + lm;
  int mb = mt * 64 + mq * 32 + 4 * half;
#pragma unroll
  for (int reg = 0; reg < 16; ++reg) {
    int m = mb + (reg & 3) + 8 * (reg >> 2);
    SWk[(size_t)m * 768 + n] = acc[reg];
  }
}

// ---------------- wprep v2: 1 block per SW row, LDS-staged coalesced -----
__global__ __launch_bounds__(256) void wprep_kernel(
    const float* __restrict__ ka, const float* __restrict__ SW,
    unsigned short* __restrict__ wBF) {
  __shared__ float rowL[4][768];
  int t = threadIdx.x;
  int row = blockIdx.x;  // grid 768: row = oc*3 + dy
  int oc = row / 3, dy = row - oc * 3;
  if (t < 192) {
#pragma unroll
    for (int k = 0; k < 4; ++k)
      *(float4*)&rowL[k][t * 4] =
          *(const float4*)(SW + (size_t)k * 589824 + (size_t)row * 768 + t * 4);
  }
  float att[8][4];
#pragma unroll
  for (int b = 0; b < 8; ++b)
#pragma unroll
    for (int k = 0; k < 4; ++k)
      att[b][k] = 0.5f / (1.f + expf(-ka[b * 4 + k]));
  __syncthreads();
  int icb = t >> 4, i = t & 15;
#pragma unroll
  for (int dx = 0; dx < 3; ++dx) {
    int col = icb * 48 + dx + 3 * i;
    float v0 = rowL[0][col], v1 = rowL[1][col], v2 = rowL[2][col],
          v3 = rowL[3][col];
    int s = dy * 3 + dx;
#pragma unroll
    for (int b = 0; b < 8; ++b) {
      float v = att[b][0] * v0 + att[b][1] * v1 + att[b][2] * v2 +
                att[b][3] * v3;
      wBF[(((size_t)(b * 16 + icb) * 9 + s) * 256 + oc) * 16 + i] =
          (unsigned short)f2bf(v);
    }
  }
}

// ---------------- conv v9 (unchanged, control): granule LDS layout -------
__global__ __launch_bounds__(256, 2) void conv_mfma_kernel(
    const float* __restrict__ x, const unsigned short* __restrict__ wBF,
    float* __restrict__ out) {
  __shared__ __align__(16) unsigned char ldsX[2][4 * 2 * 66 * 16];
  int t = threadIdx.x;
  int orig = blockIdx.x;  // grid 512
  int xcd = orig & 7, seq = orig >> 3;
  int slice = xcd * 2 + (seq >> 5);  // = b*2 + oct; XCD x owns b = x
  int pxt = seq & 31;
  int b = slice >> 1, oct = slice & 1;
  int py0 = pxt * 2, oc0 = oct * 128;
  int lane = t & 63, w = t >> 6;
  int ocq = w >> 1, pxq = w & 1;
  int n = lane & 31, half = lane >> 5;

  if (t < 128) {
    int buf = t >> 6, rem = t & 63;
    int idx = rem >> 2, word = rem & 3;
    int r = idx >> 2, icg = (idx >> 1) & 1, c = (idx & 1) ? 65 : 0;
    *(unsigned int*)(&ldsX[buf][(((r * 2 + icg) * 66) + c) * 16 + word * 4]) =
        0u;
  }

  f32x16 acc[2][2];
#pragma unroll
  for (int i = 0; i < 2; ++i)
#pragma unroll
    for (int j = 0; j < 2; ++j)
#pragma unroll
      for (int r = 0; r < 16; ++r) acc[i][j][r] = 0.f;

  int px4 = lane & 15, sub = lane >> 4;
  int iy = py0 - 1 + sub;
  bool valid = (iy >= 0 && iy < 64);
  const float* xpb =
      x + (((size_t)(b * NC + w * 4)) * 64 + (valid ? iy : 0)) * 64 + px4;
  int xwbase = (((sub * 2 + (w >> 1)) * 66) + 1 + px4) * 16 + (w & 1) * 8;
  unsigned char* xw0 = (unsigned char*)&ldsX[0][0] + xwbase;
  unsigned char* xw1 = (unsigned char*)&ldsX[1][0] + xwbase;

  float a[4][4];
#pragma unroll
  for (int j = 0; j < 4; ++j)
#pragma unroll
    for (int pp = 0; pp < 4; ++pp) a[j][pp] = 0.f;
  if (valid) {
#pragma unroll
    for (int j = 0; j < 4; ++j) {
      const float* pj = xpb + (size_t)j * 4096;
#pragma unroll
      for (int pp = 0; pp < 4; ++pp) a[j][pp] = pj[pp * 16];
    }
  }

  const uint4* wg4 = (const uint4*)wBF;
  size_t abase =
      (size_t)b * 144 * 512 + (size_t)(oc0 + ocq * 64 + n) * 2 + half;
  U4S8 pf[9][2];
#pragma unroll
  for (int i = 0; i < 9; ++i) {
    pf[i][0].u4 = wg4[abase + (size_t)i * 512];
    pf[i][1].u4 = wg4[abase + (size_t)i * 512 + 64];
  }

#pragma unroll
  for (int pp = 0; pp < 4; ++pp) {
    uint2 wv;
    wv.x = f2bf(a[0][pp]) | (f2bf(a[1][pp]) << 16);
    wv.y = f2bf(a[2][pp]) | (f2bf(a[3][pp]) << 16);
    *(uint2*)(xw0 + pp * 256) = wv;
  }
  barrier_lgkm();

  for (int icb = 0; icb < 16; ++icb) {
#pragma unroll
    for (int j = 0; j < 4; ++j)
#pragma unroll
      for (int pp = 0; pp < 4; ++pp) a[j][pp] = 0.f;
    if (icb < 15 && valid) {
      const float* p0 = xpb + (size_t)(icb + 1) * 16 * 4096;
#pragma unroll
      for (int j = 0; j < 4; ++j) {
        const float* pj = p0 + (size_t)j * 4096;
#pragma unroll
        for (int pp = 0; pp < 4; ++pp) a[j][pp] = pj[pp * 16];
      }
    }
    const unsigned char* bufR = &ldsX[icb & 1][0];
#pragma unroll
    for (int s = 0; s < 9; ++s) {
      int step = icb * 9 + s;
      int dy = s / 3, dx = s - dy * 3;
      const unsigned char* bb =
          bufR + ((((pxq + dy) * 2 + half) * 66) + n + dx) * 16;
      short8 B0 = *(const short8*)bb;
      short8 B1 = *(const short8*)(bb + 512);
      acc[0][0] = __builtin_amdgcn_mfma_f32_32x32x16_bf16(pf[s][0].s8, B0,
                                                          acc[0][0], 0, 0, 0);
      acc[0][1] = __builtin_amdgcn_mfma_f32_32x32x16_bf16(pf[s][0].s8, B1,
                                                          acc[0][1], 0, 0, 0);
      acc[1][0] = __builtin_amdgcn_mfma_f32_32x32x16_bf16(pf[s][1].s8, B0,
                                                          acc[1][0], 0, 0, 0);
      acc[1][1] = __builtin_amdgcn_mfma_f32_32x32x16_bf16(pf[s][1].s8, B1,
                                                          acc[1][1], 0, 0, 0);
      if (icb < 15) {
        pf[s][0].u4 = wg4[abase + (size_t)(step + 9) * 512];
        pf[s][1].u4 = wg4[abase + (size_t)(step + 9) * 512 + 64];
      }
    }
    if (icb < 15) {
      unsigned char* xw = (icb & 1) ? xw0 : xw1;
#pragma unroll
      for (int pp = 0; pp < 4; ++pp) {
        uint2 wv;
        wv.x = f2bf(a[0][pp]) | (f2bf(a[1][pp]) << 16);
        wv.y = f2bf(a[2][pp]) | (f2bf(a[3][pp]) << 16);
        *(uint2*)(xw + pp * 256) = wv;
      }
    }
    barrier_lgkm();
  }

  int py = py0 + pxq;
#pragma unroll
  for (int osub = 0; osub < 2; ++osub)
#pragma unroll
    for (int psub = 0; psub < 2; ++psub) {
      int OC = oc0 + ocq * 64 + osub * 32 + 4 * half;
      int pxc = psub * 32 + n;
      float* op = out + (((size_t)(b * NC + OC)) * 64 + py) * 64 + pxc;
#pragma unroll
      for (int reg = 0; reg < 16; ++reg) {
        int ocm = (reg & 3) + 8 * (reg >> 2);
        op[(size_t)ocm * 4096] = acc[osub][psub][reg];
      }
    }
}

extern "C" void kernel_launch(void* const* d_in, const int* in_sizes, int n_in,
                              void* d_out, int out_size, void* d_ws,
                              size_t ws_size, hipStream_t stream) {
  const float* x = (const float*)d_in[0];
  const float* dw = (const float*)d_in[1];
  const float* ka = (const float*)d_in[2];
  const int* fh = (const int*)d_in[3];
  const int* fw = (const int*)d_in[4];
  float* out = (float*)d_out;
  unsigned int* ws = (unsigned int*)d_ws;
  const unsigned short* specB = (const unsigned short*)d_ws;
  const unsigned short* Atw = (const unsigned short*)((char*)d_ws + 6291456);
  unsigned short* Ya = (unsigned short*)((char*)d_ws + 11010048);
  const unsigned short* T = (const unsigned short*)((char*)d_ws + 15925248);
  float* SW = (float*)d_ws;
  unsigned short* wBF = (unsigned short*)((char*)d_ws + WBF_BYTE);

  hipLaunchKernelGGL(prep_kernel, dim3(2841), dim3(256), 0, stream, dw, fh,
                     fw, ws);
  hipLaunchKernelGGL(fftA_kernel, dim3(12, 7, 8), dim3(256), 0, stream, Atw,
                     specB, Ya);
  hipLaunchKernelGGL(fftB_kernel, dim3(12, 12, KNUM), dim3(256), 0, stream, Ya,
                     T, SW);
  hipLaunchKernelGGL(wprep_kernel, dim3(768), dim3(256), 0, stream, ka, SW,
                     wBF);
  hipLaunchKernelGGL(conv_mfma_kernel, dim3(512), dim3(256), 0, stream, x,
                     wBF, out);
}